// Round 9
// baseline (1594.389 us; speedup 1.0000x reference)
//
#include <hip/hip_runtime.h>
#include <math.h>

// Problem constants (fixed by the reference)
#define BN 256     // batch N
#define TT 1000    // timesteps
#define NO 10      // obs dim
#define NS 10      // state dim
#define HID 64     // GRU hidden
#define DIN 20     // NO + NS
#define G3 192     // 3*HID
#define C_HALF_LOG2PI -0.918938533204672742f

typedef float v2f __attribute__((ext_vector_type(2)));

// broadcast lane `l`'s value of v to all lanes (l compile-time/wave-uniform)
__device__ __forceinline__ float bcast(float v, int l) {
    return __int_as_float(__builtin_amdgcn_readlane(__float_as_int(v), l));
}
__device__ __forceinline__ float rcpf(float x) { return __builtin_amdgcn_rcpf(x); }

// ---------------- Phase 1: GRU recurrence, ONE WAVE PER SAMPLE -------------
// No barriers, no LDS, no cross-wave exchange (R5/R6/R8 evidence: the 4-wave
// k-split pays an irreducible ~900 cyc/step barrier+LDS rendezvous).
// R1/R7 post-mortem: per-lane ARRAYS of 64 never get register-promoted (SROA
// cap) -> scratch storm. Fix: 64 NAMED v2f variables via macro expansion --
// pure SSA, nothing for SROA to bail on. ~350 VGPR; waves_per_eu(1,1) gives
// the 512 budget (m08: no spill through ~450).
// Gate packing: wrzK = {Wh_r[k], Wh_z[k]}, wnmK = {Wh_n[k], Wmv[k]} ->
// v_pk_fma_f32; the mu/var output projection rides the second pk slot free.
__global__
__attribute__((amdgpu_flat_work_group_size(64, 64), amdgpu_waves_per_eu(1, 1)))
void gru_p1(const float* __restrict__ Yi, const float* __restrict__ Xh,
            const float* __restrict__ Wi, const float* __restrict__ Wh,
            const float* __restrict__ bi, const float* __restrict__ bh,
            const float* __restrict__ Wmu, const float* __restrict__ Wvar,
            float* __restrict__ mv_out) {
    const int lane = threadIdx.x;   // hidden unit index
    const int n = blockIdx.x;

    const float* ybase = Yi + (size_t)n * TT * NO;
    const float* xbase = Xh + (size_t)n * TT * NS;
    float* obase = mv_out + (size_t)n * TT * DIN;

    // packed mv weight element for hidden unit k (this lane's output column):
    // lanes 0..9 -> W_mu col lane ; 10..19 -> W_var col lane-10 ; else 0
#define WMV(k) ((lane < NS) ? Wmu[(k) * NS + lane] \
              : (lane < 2 * NS) ? Wvar[(k) * NS + (lane - NS)] : 0.0f)
#define WDEF(k) \
    const v2f wrz##k = {Wh[(k) * G3 + lane], Wh[(k) * G3 + 64 + lane]}; \
    const v2f wnm##k = {Wh[(k) * G3 + 128 + lane], WMV(k)};
    WDEF(0)  WDEF(1)  WDEF(2)  WDEF(3)  WDEF(4)  WDEF(5)  WDEF(6)  WDEF(7)
    WDEF(8)  WDEF(9)  WDEF(10) WDEF(11) WDEF(12) WDEF(13) WDEF(14) WDEF(15)
    WDEF(16) WDEF(17) WDEF(18) WDEF(19) WDEF(20) WDEF(21) WDEF(22) WDEF(23)
    WDEF(24) WDEF(25) WDEF(26) WDEF(27) WDEF(28) WDEF(29) WDEF(30) WDEF(31)
    WDEF(32) WDEF(33) WDEF(34) WDEF(35) WDEF(36) WDEF(37) WDEF(38) WDEF(39)
    WDEF(40) WDEF(41) WDEF(42) WDEF(43) WDEF(44) WDEF(45) WDEF(46) WDEF(47)
    WDEF(48) WDEF(49) WDEF(50) WDEF(51) WDEF(52) WDEF(53) WDEF(54) WDEF(55)
    WDEF(56) WDEF(57) WDEF(58) WDEF(59) WDEF(60) WDEF(61) WDEF(62) WDEF(63)

#define IDEF(d) \
    const v2f wirz##d = {Wi[(d) * G3 + lane], Wi[(d) * G3 + 64 + lane]}; \
    const float win##d = Wi[(d) * G3 + 128 + lane];
    IDEF(0)  IDEF(1)  IDEF(2)  IDEF(3)  IDEF(4)  IDEF(5)  IDEF(6)  IDEF(7)
    IDEF(8)  IDEF(9)  IDEF(10) IDEF(11) IDEF(12) IDEF(13) IDEF(14) IDEF(15)
    IDEF(16) IDEF(17) IDEF(18) IDEF(19)

    const v2f brz = {bi[lane] + bh[lane], bi[64 + lane] + bh[64 + lane]};
    const float bxn = bi[128 + lane];
    const float bhn = bh[128 + lane];

    // input loader: lane d<20 holds x_t[d] = concat(y_t, xhat_t)[d]
    auto loadx = [&](int t) -> float {
        float v = 0.0f;
        if (lane < NO) v = ybase[(size_t)t * NO + lane];
        else if (lane < DIN) v = xbase[(size_t)t * NS + (lane - NO)];
        return v;
    };

    float h = 0.0f;
    float xq0 = loadx(0), xq1 = loadx(1);   // 2-deep register prefetch

    // one GRU step; x = step input (lanes 0..19), t = step index.
    // Output row t-1 (projection of h_{t-1}) rides this step's broadcasts.
    auto step = [&](float x, int t) {
        v2f a0rz = brz, a1rz = {0.0f, 0.0f}, a2rz = {0.0f, 0.0f}, a3rz = {0.0f, 0.0f};
        v2f a0nm = {0.0f, 0.0f}, a1nm = {0.0f, 0.0f}, a2nm = {0.0f, 0.0f}, a3nm = {0.0f, 0.0f};
        float ax0 = bxn, ax1 = 0.0f, ax2 = 0.0f, ax3 = 0.0f;
        // input projection (20 dims, 4-way rotated accumulators)
#define XD(d, j) { const float s_ = bcast(x, d); \
        a##j##rz += s_ * wirz##d; ax##j = fmaf(s_, win##d, ax##j); }
        XD(0, 0)  XD(1, 1)  XD(2, 2)  XD(3, 3)
        XD(4, 0)  XD(5, 1)  XD(6, 2)  XD(7, 3)
        XD(8, 0)  XD(9, 1)  XD(10, 2) XD(11, 3)
        XD(12, 0) XD(13, 1) XD(14, 2) XD(15, 3)
        XD(16, 0) XD(17, 1) XD(18, 2) XD(19, 3)
        // hidden projection (64 k, 4-way rotated)
#define HK(k, j) { const float s_ = bcast(h, k); \
        a##j##rz += s_ * wrz##k; a##j##nm += s_ * wnm##k; }
        HK(0, 0)  HK(1, 1)  HK(2, 2)  HK(3, 3)
        HK(4, 0)  HK(5, 1)  HK(6, 2)  HK(7, 3)
        HK(8, 0)  HK(9, 1)  HK(10, 2) HK(11, 3)
        HK(12, 0) HK(13, 1) HK(14, 2) HK(15, 3)
        HK(16, 0) HK(17, 1) HK(18, 2) HK(19, 3)
        HK(20, 0) HK(21, 1) HK(22, 2) HK(23, 3)
        HK(24, 0) HK(25, 1) HK(26, 2) HK(27, 3)
        HK(28, 0) HK(29, 1) HK(30, 2) HK(31, 3)
        HK(32, 0) HK(33, 1) HK(34, 2) HK(35, 3)
        HK(36, 0) HK(37, 1) HK(38, 2) HK(39, 3)
        HK(40, 0) HK(41, 1) HK(42, 2) HK(43, 3)
        HK(44, 0) HK(45, 1) HK(46, 2) HK(47, 3)
        HK(48, 0) HK(49, 1) HK(50, 2) HK(51, 3)
        HK(52, 0) HK(53, 1) HK(54, 2) HK(55, 3)
        HK(56, 0) HK(57, 1) HK(58, 2) HK(59, 3)
        HK(60, 0) HK(61, 1) HK(62, 2) HK(63, 3)
        const v2f arz = (a0rz + a1rz) + (a2rz + a3rz);
        const v2f anm = (a0nm + a1nm) + (a2nm + a3nm);
        const float ar = arz.x, az = arz.y;
        const float anx = (ax0 + ax1) + (ax2 + ax3);
        const float anh = bhn + anm.x;
        // output row t-1: mv projection of h_{t-1} (fire-and-forget store)
        if (t > 0 && lane < DIN)
            obase[(size_t)(t - 1) * DIN + lane] = anm.y;

        float r = rcpf(1.0f + __expf(-ar));
        float z = rcpf(1.0f + __expf(-az));
        float pre = fmaf(r, anh, anx);
        float e2 = __expf(2.0f * pre);          // inf-safe: nn -> +/-1
        float nn = 1.0f - 2.0f * rcpf(e2 + 1.0f);
        h = fmaf(z, h - nn, nn);                // (1-z)*n + z*h
    };

#pragma unroll 1
    for (int tb = 0; tb < TT; tb += 2) {
        // issue next prefetches first (~2 steps / ~1100 cyc of cover)
        float p0 = (tb + 2 < TT) ? loadx(tb + 2) : 0.0f;
        float p1 = (tb + 3 < TT) ? loadx(tb + 3) : 0.0f;
        step(xq0, tb);
        step(xq1, tb + 1);
        xq0 = p0; xq1 = p1;
    }

    // epilogue: output row 999 from h_999
    {
        float pm = 0.0f;
#define HM(k) pm = fmaf(bcast(h, k), wnm##k.y, pm);
        HM(0)  HM(1)  HM(2)  HM(3)  HM(4)  HM(5)  HM(6)  HM(7)
        HM(8)  HM(9)  HM(10) HM(11) HM(12) HM(13) HM(14) HM(15)
        HM(16) HM(17) HM(18) HM(19) HM(20) HM(21) HM(22) HM(23)
        HM(24) HM(25) HM(26) HM(27) HM(28) HM(29) HM(30) HM(31)
        HM(32) HM(33) HM(34) HM(35) HM(36) HM(37) HM(38) HM(39)
        HM(40) HM(41) HM(42) HM(43) HM(44) HM(45) HM(46) HM(47)
        HM(48) HM(49) HM(50) HM(51) HM(52) HM(53) HM(54) HM(55)
        HM(56) HM(57) HM(58) HM(59) HM(60) HM(61) HM(62) HM(63)
        if (lane < DIN)
            obase[(size_t)(TT - 1) * DIN + lane] = pm;
    }
}

// ---------------- Phase 2: per-(n,t) Gaussian log-lik (proven R6 path) -----
__global__ __launch_bounds__(256)
void lik_p2(const float* __restrict__ Yi, const float* __restrict__ Cw,
            const float* __restrict__ Hm, const float* __restrict__ mu_w,
            const float* __restrict__ b_mu, const float* __restrict__ b_var,
            const float* __restrict__ mv_in, float* __restrict__ out) {
    __shared__ float sH[NO * NS];
    __shared__ float smw[NO], sbm[NS], sbv[NS];
    __shared__ float ssum[4];
    const int tid = threadIdx.x;
    if (tid < NO * NS) sH[tid] = Hm[tid];
    if (tid < NO) smw[tid] = mu_w[tid];
    if (tid < NS) { sbm[tid] = b_mu[tid]; sbv[tid] = b_var[tid]; }
    __syncthreads();

    const int gid = blockIdx.x * 256 + tid;   // 0 .. BN*TT-1
    float contrib = 0.0f;
    if (gid < BN * TT) {
        const int n = gid / TT;
        const float* mv = mv_in + (size_t)gid * DIN;
        float mu[NS], va[NS];
#pragma unroll
        for (int i = 0; i < NS; ++i) {
            mu[i] = mv[i] + sbm[i];
            float x = mv[NS + i] + sbv[i];
            va[i] = (x > 0.0f) ? (x + log1pf(__expf(-x))) : log1pf(__expf(x));
        }
        const float* y = Yi + (size_t)gid * NO;
        float e[NO];
#pragma unroll
        for (int i = 0; i < NO; ++i) {
            float m = smw[i];
#pragma unroll
            for (int j = 0; j < NS; ++j) m = fmaf(sH[i * NS + j], mu[j], m);
            e[i] = y[i] - m;
        }
        // M = H diag(va) H^T + Cw (lower triangle only)
        float M[NO][NO];
        const float* cw = Cw + (size_t)n * NO * NO;
#pragma unroll
        for (int i = 0; i < NO; ++i)
#pragma unroll
            for (int j = 0; j <= i; ++j) M[i][j] = cw[i * NO + j];
#pragma unroll
        for (int l = 0; l < NS; ++l) {
            float vl = va[l];
            float hv[NO];
#pragma unroll
            for (int i = 0; i < NO; ++i) hv[i] = sH[i * NS + l];
#pragma unroll
            for (int i = 0; i < NO; ++i) {
                float hvi = hv[i] * vl;
#pragma unroll
                for (int j = 0; j <= i; ++j) M[i][j] = fmaf(hvi, hv[j], M[i][j]);
            }
        }
        // Cholesky; logdet = log(prod d_j); forward solve uses 1/L_jj = rs
        float dprod = 1.0f;
        float drs[NO];
#pragma unroll
        for (int j = 0; j < NO; ++j) {
            float d = M[j][j];
#pragma unroll
            for (int k = 0; k < j; ++k) d = fmaf(-M[j][k], M[j][k], d);
            dprod *= d;
            float rs = __frsqrt_rn(d);
            drs[j] = rs;
#pragma unroll
            for (int i = j + 1; i < NO; ++i) {
                float v = M[i][j];
#pragma unroll
                for (int k = 0; k < j; ++k) v = fmaf(-M[i][k], M[j][k], v);
                M[i][j] = v * rs;
            }
        }
        const float logdet = __logf(dprod);
        float wv[NO];
        float quad = 0.0f;
#pragma unroll
        for (int i = 0; i < NO; ++i) {
            float v = e[i];
#pragma unroll
            for (int k = 0; k < i; ++k) v = fmaf(-M[i][k], wv[k], v);
            wv[i] = v * drs[i];
            quad = fmaf(wv[i], wv[i], quad);
        }
        const float SCALE = 0.5f / ((float)BN * (float)TT * (float)NO);
        contrib = -(logdet + quad) * SCALE;
    }

    // block reduction: wave shuffle, LDS across 4 waves, one atomic
#pragma unroll
    for (int off = 32; off > 0; off >>= 1) contrib += __shfl_down(contrib, off);
    if ((tid & 63) == 0) ssum[tid >> 6] = contrib;
    __syncthreads();
    if (tid == 0) {
        float s = ssum[0] + ssum[1] + ssum[2] + ssum[3];
        if (blockIdx.x == 0) s += C_HALF_LOG2PI;   // d_out zeroed pre-launch
        atomicAdd(out, s);
    }
}

// ---------------- launch ---------------------------------------------------
extern "C" void kernel_launch(void* const* d_in, const int* in_sizes, int n_in,
                              void* d_out, int out_size, void* d_ws, size_t ws_size,
                              hipStream_t stream) {
    const float* Yi    = (const float*)d_in[0];
    const float* Xh    = (const float*)d_in[1];
    const float* Cw    = (const float*)d_in[2];
    const float* Hm    = (const float*)d_in[3];
    const float* mu_w  = (const float*)d_in[4];
    const float* Wi    = (const float*)d_in[5];
    const float* Wh    = (const float*)d_in[6];
    const float* bi    = (const float*)d_in[7];
    const float* bh    = (const float*)d_in[8];
    const float* W_mu  = (const float*)d_in[9];
    const float* b_mu  = (const float*)d_in[10];
    const float* W_var = (const float*)d_in[11];
    const float* b_var = (const float*)d_in[12];
    float* out = (float*)d_out;
    float* mv  = (float*)d_ws;   // [BN*TT*DIN] floats = 20.48 MB

    hipMemsetAsync(d_out, 0, sizeof(float), stream);
    gru_p1<<<dim3(BN), dim3(64), 0, stream>>>(Yi, Xh, Wi, Wh, bi, bh,
                                              W_mu, W_var, mv);
    lik_p2<<<dim3((BN * TT + 255) / 256), dim3(256), 0, stream>>>(
        Yi, Cw, Hm, mu_w, b_mu, b_var, mv, out);
}

// Round 10
// 603.377 us; speedup vs baseline: 2.6424x; 2.6424x over previous
//
#include <hip/hip_runtime.h>
#include <math.h>

// Problem constants (fixed by the reference)
#define BN 256     // batch N
#define TT 1000    // timesteps
#define NO 10      // obs dim
#define NS 10      // state dim
#define HID 64     // GRU hidden
#define DIN 20     // NO + NS
#define G3 192     // 3*HID
#define SPB 16     // samples per block (MFMA M)
#define NB (BN / SPB)
#define GS 8       // steps per staged group
#define NG 125     // groups
#define C_HALF_LOG2PI -0.918938533204672742f

typedef _Float16 f16x8 __attribute__((ext_vector_type(8)));
typedef float f32x4 __attribute__((ext_vector_type(4)));

__device__ __forceinline__ float rcpf(float x) { return __builtin_amdgcn_rcpf(x); }

// Workgroup barrier WITHOUT the vmcnt(0) drain __syncthreads() emits.
__device__ __forceinline__ void sync_lds() {
    asm volatile("s_waitcnt lgkmcnt(0)\n\ts_barrier" ::: "memory");
}

__device__ __forceinline__ f32x4 mfma16(f16x8 a, f16x8 b, f32x4 c) {
    return __builtin_amdgcn_mfma_f32_16x16x32_f16(a, b, c, 0, 0, 0);
}

// ---------------- Phase 1: GRU recurrence as batched MFMA ------------------
// 16 samples per block (MFMA M=16), 4 waves. Per step, wave w computes gate
// tiles for units 16w..16w+15 via 9 mfma_f32_16x16x32_f16 (r,z fused x+h;
// nx x-only; nh h-only -- r multiplies only h-part+bias per GRU def), plus
// mv tiles (h_{t-1} @ [W_mu|W_var]) on waves 0/1 -> output row t-1 directly
// from D regs. C/D layout: col=lane&15 (unit), row=quad*4+reg (sample) ->
// each lane owns (1 unit x 4 samples): nonlinearity in-register, h written
// back to LDS in A-layout f16. ONE lgkmcnt-only barrier per step, shared by
// 16 samples (R6's ~900cy/step rendezvous amortized 16x).
// R9 lesson: 256 addressable VGPRs is an architectural cap -- weights here
// are ~35 regs of B-frags, far under it.
__global__ __attribute__((amdgpu_flat_work_group_size(256, 256)))
void gru_mfma(const float* __restrict__ Yi, const float* __restrict__ Xh,
              const float* __restrict__ Wi, const float* __restrict__ Wh,
              const float* __restrict__ bi, const float* __restrict__ bh,
              const float* __restrict__ Wmu, const float* __restrict__ Wvar,
              float* __restrict__ mv_out) {
    const int tid = threadIdx.x;
    const int lane = tid & 63;
    const int w = tid >> 6;         // wave 0..3
    const int c = lane & 15;        // D col (unit offset) / A row (sample)
    const int q = lane >> 4;        // quad

    // h in A-layout [sample][unit], f16, row-padded to 72 (144 B: 16B-mult,
    // bank stride 36 -> 2-way max). x staged per group [step][sample][dim],
    // padded to 40 (80 B rows; dims 20..39 stay zero for the K=32 pad).
    __shared__ _Float16 hbuf[2][SPB][72];
    __shared__ _Float16 xbuf[2][GS][SPB][40];

    const int base = blockIdx.x * SPB;

    // ---- zero-init LDS (pads must be 0), then barrier before staging ----
    {
        int* p = (int*)&hbuf[0][0][0];
        for (int i = tid; i < (int)(sizeof(hbuf) / 4); i += 256) p[i] = 0;
        int* p2 = (int*)&xbuf[0][0][0][0];
        for (int i = tid; i < (int)(sizeof(xbuf) / 4); i += 256) p2[i] = 0;
    }
    sync_lds();

    // ---- B-fragments (registers). B[k][n]: lane holds k=quad*8+j, n=c ----
    const int col_g = 16 * w + c;   // this wave's gate-unit column
    f16x8 fWr0, fWr1, fWz0, fWz1, fWn0, fWn1;  // Wh r/z/nh, K-halves
    f16x8 fIr, fIz, fIn;                        // Wi r/z/nx (K=32, pad>=20)
    f16x8 fM0, fM1;                             // [W_mu|W_var] (waves 0/1)
#pragma unroll
    for (int j = 0; j < 8; ++j) {
        const int k0 = 8 * q + j;
        const int k1 = 32 + 8 * q + j;
        fWr0[j] = (_Float16)Wh[k0 * G3 + col_g];
        fWr1[j] = (_Float16)Wh[k1 * G3 + col_g];
        fWz0[j] = (_Float16)Wh[k0 * G3 + 64 + col_g];
        fWz1[j] = (_Float16)Wh[k1 * G3 + 64 + col_g];
        fWn0[j] = (_Float16)Wh[k0 * G3 + 128 + col_g];
        fWn1[j] = (_Float16)Wh[k1 * G3 + 128 + col_g];
        fIr[j] = (k0 < DIN) ? (_Float16)Wi[k0 * G3 + col_g] : (_Float16)0.0f;
        fIz[j] = (k0 < DIN) ? (_Float16)Wi[k0 * G3 + 64 + col_g] : (_Float16)0.0f;
        fIn[j] = (k0 < DIN) ? (_Float16)Wi[k0 * G3 + 128 + col_g] : (_Float16)0.0f;
        float m0 = 0.0f, m1 = 0.0f;
        const int d = 16 * w + c;   // mv output dim (waves 0/1)
        if (w < 2 && d < DIN) {
            m0 = (d < NS) ? Wmu[k0 * NS + d] : Wvar[k0 * NS + (d - NS)];
            m1 = (d < NS) ? Wmu[k1 * NS + d] : Wvar[k1 * NS + (d - NS)];
        }
        fM0[j] = (_Float16)m0;
        fM1[j] = (_Float16)m1;
    }
    const int u = col_g;            // this lane's unit
    const float b_r = bi[u] + bh[u];
    const float b_z = bi[64 + u] + bh[64 + u];
    const float bxn = bi[128 + u];
    const float bhn = bh[128 + u];

    // ---- x staging role: one (step,sample) row per thread ----
    const int sty = (tid < 128) ? tid : tid - 128;
    const int ss = sty >> 4;        // step within group
    const int sm = sty & 15;        // sample within block
    const float* srow = (tid < 128) ? (Yi + (size_t)(base + sm) * TT * NO)
                                    : (Xh + (size_t)(base + sm) * TT * NS);
    const int k0s = (tid < 128) ? 0 : 10;

    // stage group 0 (rows are 40 B contiguous in global)
    {
        const float* rp = srow + (size_t)ss * 10;
#pragma unroll
        for (int e = 0; e < 10; ++e)
            xbuf[0][ss][sm][k0s + e] = (_Float16)rp[e];
    }
    sync_lds();

    float hprev[4] = {0.0f, 0.0f, 0.0f, 0.0f};  // this lane's h (unit u, 4 samples)

#pragma unroll 1
    for (int g = 0; g < NG; ++g) {
        // issue next group's loads now; consumed (vmcnt-waited) at s==7
        float st[10];
        const bool do_ld = (g + 1 < NG);
        if (do_ld) {
            const float* rp = srow + (size_t)(8 * (g + 1) + ss) * 10;
#pragma unroll
            for (int e = 0; e < 10; ++e) st[e] = rp[e];
        }
#pragma unroll
        for (int s = 0; s < GS; ++s) {
            const int t = 8 * g + s;
            const int p = t & 1;
            // A-frags: h_{t-1} (2 K-halves) + x_t
            const f16x8 ha0 = *(const f16x8*)&hbuf[p][c][8 * q];
            const f16x8 ha1 = *(const f16x8*)&hbuf[p][c][32 + 8 * q];
            const f16x8 xa  = *(const f16x8*)&xbuf[g & 1][s][c][8 * q];
            f32x4 Dr = {0, 0, 0, 0}, Dz = {0, 0, 0, 0};
            f32x4 Dnx = {0, 0, 0, 0}, Dnh = {0, 0, 0, 0};
            Dr  = mfma16(xa, fIr, Dr);
            Dz  = mfma16(xa, fIz, Dz);
            Dnx = mfma16(xa, fIn, Dnx);
            Dr  = mfma16(ha0, fWr0, Dr);
            Dz  = mfma16(ha0, fWz0, Dz);
            Dnh = mfma16(ha0, fWn0, Dnh);
            Dr  = mfma16(ha1, fWr1, Dr);
            Dz  = mfma16(ha1, fWz1, Dz);
            Dnh = mfma16(ha1, fWn1, Dnh);
            f32x4 Dmv = {0, 0, 0, 0};
            if (w < 2) {
                Dmv = mfma16(ha0, fM0, Dmv);
                Dmv = mfma16(ha1, fM1, Dmv);
            }
            // nonlinearity + h update + h write (lane = unit u, samples 4q+j)
#pragma unroll
            for (int j = 0; j < 4; ++j) {
                const float ar = Dr[j] + b_r;
                const float az = Dz[j] + b_z;
                const float ax = Dnx[j] + bxn;
                const float ah = Dnh[j] + bhn;
                const float r = rcpf(1.0f + __expf(-ar));
                const float z = rcpf(1.0f + __expf(-az));
                const float pre = fmaf(r, ah, ax);
                const float e2 = __expf(2.0f * pre);   // inf-safe
                const float nn = 1.0f - 2.0f * rcpf(e2 + 1.0f);
                const float hn = fmaf(z, hprev[j] - nn, nn);
                hprev[j] = hn;
                hbuf[p ^ 1][4 * q + j][u] = (_Float16)hn;
            }
            // mv output row t-1 straight from D regs (fire-and-forget)
            if (t > 0 && w < 2) {
                const int d0 = 16 * w + c;
                if (d0 < DIN) {
#pragma unroll
                    for (int j = 0; j < 4; ++j) {
                        const size_t row = (size_t)(base + 4 * q + j) * TT + (t - 1);
                        mv_out[row * DIN + d0] = Dmv[j];
                    }
                }
            }
            // stage next group's x just before the group's last barrier
            if (s == GS - 1 && do_ld) {
#pragma unroll
                for (int e = 0; e < 10; ++e)
                    xbuf[(g + 1) & 1][ss][sm][k0s + e] = (_Float16)st[e];
            }
            sync_lds();
        }
    }

    // epilogue: mv of h_999 (written to hbuf[0] at t=999; final barrier done)
    if (w < 2) {
        const f16x8 ha0 = *(const f16x8*)&hbuf[0][c][8 * q];
        const f16x8 ha1 = *(const f16x8*)&hbuf[0][c][32 + 8 * q];
        f32x4 Dmv = {0, 0, 0, 0};
        Dmv = mfma16(ha0, fM0, Dmv);
        Dmv = mfma16(ha1, fM1, Dmv);
        const int d0 = 16 * w + c;
        if (d0 < DIN) {
#pragma unroll
            for (int j = 0; j < 4; ++j) {
                const size_t row = (size_t)(base + 4 * q + j) * TT + (TT - 1);
                mv_out[row * DIN + d0] = Dmv[j];
            }
        }
    }
}

// ---------------- Phase 2: per-(n,t) Gaussian log-lik (proven R6 path) -----
__global__ __launch_bounds__(256)
void lik_p2(const float* __restrict__ Yi, const float* __restrict__ Cw,
            const float* __restrict__ Hm, const float* __restrict__ mu_w,
            const float* __restrict__ b_mu, const float* __restrict__ b_var,
            const float* __restrict__ mv_in, float* __restrict__ out) {
    __shared__ float sH[NO * NS];
    __shared__ float smw[NO], sbm[NS], sbv[NS];
    __shared__ float ssum[4];
    const int tid = threadIdx.x;
    if (tid < NO * NS) sH[tid] = Hm[tid];
    if (tid < NO) smw[tid] = mu_w[tid];
    if (tid < NS) { sbm[tid] = b_mu[tid]; sbv[tid] = b_var[tid]; }
    __syncthreads();

    const int gid = blockIdx.x * 256 + tid;   // 0 .. BN*TT-1
    float contrib = 0.0f;
    if (gid < BN * TT) {
        const int n = gid / TT;
        const float* mv = mv_in + (size_t)gid * DIN;
        float mu[NS], va[NS];
#pragma unroll
        for (int i = 0; i < NS; ++i) {
            mu[i] = mv[i] + sbm[i];
            float x = mv[NS + i] + sbv[i];
            va[i] = (x > 0.0f) ? (x + log1pf(__expf(-x))) : log1pf(__expf(x));
        }
        const float* y = Yi + (size_t)gid * NO;
        float e[NO];
#pragma unroll
        for (int i = 0; i < NO; ++i) {
            float m = smw[i];
#pragma unroll
            for (int j = 0; j < NS; ++j) m = fmaf(sH[i * NS + j], mu[j], m);
            e[i] = y[i] - m;
        }
        // M = H diag(va) H^T + Cw (lower triangle only)
        float M[NO][NO];
        const float* cw = Cw + (size_t)n * NO * NO;
#pragma unroll
        for (int i = 0; i < NO; ++i)
#pragma unroll
            for (int j = 0; j <= i; ++j) M[i][j] = cw[i * NO + j];
#pragma unroll
        for (int l = 0; l < NS; ++l) {
            float vl = va[l];
            float hv[NO];
#pragma unroll
            for (int i = 0; i < NO; ++i) hv[i] = sH[i * NS + l];
#pragma unroll
            for (int i = 0; i < NO; ++i) {
                float hvi = hv[i] * vl;
#pragma unroll
                for (int j = 0; j <= i; ++j) M[i][j] = fmaf(hvi, hv[j], M[i][j]);
            }
        }
        // Cholesky; logdet = log(prod d_j); forward solve uses 1/L_jj = rs
        float dprod = 1.0f;
        float drs[NO];
#pragma unroll
        for (int j = 0; j < NO; ++j) {
            float d = M[j][j];
#pragma unroll
            for (int k = 0; k < j; ++k) d = fmaf(-M[j][k], M[j][k], d);
            dprod *= d;
            float rs = __frsqrt_rn(d);
            drs[j] = rs;
#pragma unroll
            for (int i = j + 1; i < NO; ++i) {
                float v = M[i][j];
#pragma unroll
                for (int k = 0; k < j; ++k) v = fmaf(-M[i][k], M[j][k], v);
                M[i][j] = v * rs;
            }
        }
        const float logdet = __logf(dprod);
        float wv[NO];
        float quad = 0.0f;
#pragma unroll
        for (int i = 0; i < NO; ++i) {
            float v = e[i];
#pragma unroll
            for (int k = 0; k < i; ++k) v = fmaf(-M[i][k], wv[k], v);
            wv[i] = v * drs[i];
            quad = fmaf(wv[i], wv[i], quad);
        }
        const float SCALE = 0.5f / ((float)BN * (float)TT * (float)NO);
        contrib = -(logdet + quad) * SCALE;
    }

#pragma unroll
    for (int off = 32; off > 0; off >>= 1) contrib += __shfl_down(contrib, off);
    if ((tid & 63) == 0) ssum[tid >> 6] = contrib;
    __syncthreads();
    if (tid == 0) {
        float s = ssum[0] + ssum[1] + ssum[2] + ssum[3];
        if (blockIdx.x == 0) s += C_HALF_LOG2PI;   // d_out zeroed pre-launch
        atomicAdd(out, s);
    }
}

// ---------------- launch ---------------------------------------------------
extern "C" void kernel_launch(void* const* d_in, const int* in_sizes, int n_in,
                              void* d_out, int out_size, void* d_ws, size_t ws_size,
                              hipStream_t stream) {
    const float* Yi    = (const float*)d_in[0];
    const float* Xh    = (const float*)d_in[1];
    const float* Cw    = (const float*)d_in[2];
    const float* Hm    = (const float*)d_in[3];
    const float* mu_w  = (const float*)d_in[4];
    const float* Wi    = (const float*)d_in[5];
    const float* Wh    = (const float*)d_in[6];
    const float* bi    = (const float*)d_in[7];
    const float* bh    = (const float*)d_in[8];
    const float* W_mu  = (const float*)d_in[9];
    const float* b_mu  = (const float*)d_in[10];
    const float* W_var = (const float*)d_in[11];
    const float* b_var = (const float*)d_in[12];
    float* out = (float*)d_out;
    float* mv  = (float*)d_ws;   // [BN*TT*DIN] floats = 20.48 MB

    hipMemsetAsync(d_out, 0, sizeof(float), stream);
    gru_mfma<<<dim3(NB), dim3(256), 0, stream>>>(Yi, Xh, Wi, Wh, bi, bh,
                                                 W_mu, W_var, mv);
    lik_p2<<<dim3((BN * TT + 255) / 256), dim3(256), 0, stream>>>(
        Yi, Cw, Hm, mu_w, b_mu, b_var, mv, out);
}